// Round 4
// baseline (258.625 us; speedup 1.0000x reference)
//
#include <hip/hip_runtime.h>

// ---------------- problem constants ----------------
#define BATCH   65536
#define NPAGES  4096
#define KD      128

// ws layout (bytes). Total 18,309,120 B (~17.5 MB).
#define OFF_Q    0u          // Q bf16 [65536][128], pre-scaled by invt*log2e  16 MB
#define OFF_K    16777216u   // K bf16, 64-page chunks, XOR-swizzled            1 MB
#define OFF_V    17825792u   // V^T bf16 [48][4096] (aug: ones col 40)        384 KB
#define OFF_W1T  18219008u   // W1^T bf16 [256][48] (k padded 36->48)          24 KB
#define OFF_W2T  18243584u   // W2^T bf16 [128][256]                           64 KB
#define WS_NEEDED 18309120u

typedef short          bfr8   __attribute__((ext_vector_type(8)));
typedef unsigned short u16x8  __attribute__((ext_vector_type(8)));
typedef unsigned short u16x4  __attribute__((ext_vector_type(4)));
typedef unsigned int   u32x4  __attribute__((ext_vector_type(4)));
typedef float          f32x16v __attribute__((ext_vector_type(16)));

__device__ __forceinline__ unsigned short f2bf(float x){
  unsigned int u = __builtin_bit_cast(unsigned int, x);
  unsigned int r = (u + 0x7fffu + ((u >> 16) & 1u)) >> 16;   // RNE
  return (unsigned short)r;
}
__device__ __forceinline__ float sigmoidf_(float x){ return 1.0f / (1.0f + __expf(-x)); }

__device__ __forceinline__ f32x16v mfma32(bfr8 a, bfr8 b, f32x16v c){
  return __builtin_amdgcn_mfma_f32_32x32x16_bf16(a, b, c, 0, 0, 0);
}
__device__ __forceinline__ f32x16v zero16(){
  f32x16v v;
  #pragma unroll
  for (int i = 0; i < 16; ++i) v[i] = 0.f;
  return v;
}

// exp2 + pack one 32-key S-tile into two PV A-fragments (keys 0-15, 16-31).
// Q was pre-scaled by invt*log2e, so P = exp2(S) directly (1 trans op/elem).
__device__ __forceinline__ void tile_pack(const f32x16v& s, bfr8& paA, bfr8& paB){
  unsigned w[8];
  #pragma unroll
  for (int p = 0; p < 8; ++p){
    float a = exp2f(s[2*p]);
    float b = exp2f(s[2*p+1]);
    asm("v_cvt_pk_bf16_f32 %0, %1, %2" : "=v"(w[p]) : "v"(a), "v"(b));
  }
  asm("v_permlane32_swap_b32 %0, %1" : "+v"(w[0]), "+v"(w[2]));
  asm("v_permlane32_swap_b32 %0, %1" : "+v"(w[1]), "+v"(w[3]));
  asm("v_permlane32_swap_b32 %0, %1" : "+v"(w[4]), "+v"(w[6]));
  asm("v_permlane32_swap_b32 %0, %1" : "+v"(w[5]), "+v"(w[7]));
  u32x4 t0 = {w[0], w[1], w[2], w[3]};
  u32x4 t1 = {w[4], w[5], w[6], w[7]};
  paA = __builtin_bit_cast(bfr8, t0);
  paB = __builtin_bit_cast(bfr8, t1);
}

// ---------------- prep: bf16 conversions / layouts ----------------
__global__ void prep_kernel(const float* __restrict__ mappings, const float* __restrict__ keys,
                            const float* __restrict__ perms, const float* __restrict__ W1,
                            const float* __restrict__ W2, char* __restrict__ ws){
  int t = blockIdx.x * 256 + threadIdx.x;
  if (t < 65536){                       // K: 4096 pages x 16 granules of 8 cols
    int p = t >> 4, c8 = t & 15;
    const float* src = keys + (size_t)p * 128 + c8 * 8;
    u16x8 val;
    #pragma unroll
    for (int j = 0; j < 8; ++j) val[j] = f2bf(src[j]);
    int r = p & 63, chunk = p >> 6;
    int byteoff = (r * 256 + c8 * 16) ^ ((r & 7) << 4);   // pre-swizzle (involution)
    *(u16x8*)(ws + OFF_K + (size_t)chunk * 16384 + byteoff) = val;
  } else if (t < 65536 + 12288){        // W1^T [256][48], k>=36 zero
    int i = t - 65536; int cc = i / 48, k = i - cc * 48;
    float v = (k < 36) ? W1[(size_t)k * 256 + cc] : 0.0f;
    ((unsigned short*)(ws + OFF_W1T))[cc * 48 + k] = f2bf(v);
  } else if (t < 65536 + 12288 + 32768){ // W2^T [128][256]
    int i = t - (65536 + 12288); int cc = i >> 8, k = i & 255;
    ((unsigned short*)(ws + OFF_W2T))[cc * 256 + k] = f2bf(W2[(size_t)k * 128 + cc]);
  } else {                              // V^T [48][4096]: rows 0..35 map[36+j], 36..39 perms, 40 ones, 41..47 zero
    int i = t - (65536 + 12288 + 32768); int j = i >> 12, p = i & 4095;
    float v;
    if (j < 36)      v = mappings[(size_t)p * 72 + 36 + j];
    else if (j < 40) v = perms[(size_t)p * 4 + (j - 36)];
    else if (j == 40) v = 1.0f;
    else             v = 0.0f;
    ((unsigned short*)(ws + OFF_V))[j * 4096 + p] = f2bf(v);
  }
}

// ---------------- MLP: query = gelu(pb@W1+b1)@W2+b2 -> Q bf16 (pre-scaled) --
__global__ __launch_bounds__(256, 2) void mlp_kernel(const float* __restrict__ vab,
    const float* __restrict__ b1, const float* __restrict__ b2,
    const float* __restrict__ temp_p, char* __restrict__ ws, float* __restrict__ out){
  __shared__ __align__(16) unsigned short pb_lds[128 * 64];   // swizzled bf16, 16 KB
  __shared__ __align__(16) unsigned short h_lds[128 * 256];   // swizzled bf16, 64 KB
  const int tid = threadIdx.x;
  const int bb = blockIdx.x * 128;
  const float qscale = 1.44269504088896f / fmaxf(fabsf(temp_p[0]), 0.1f);

  for (int i = tid; i < 128 * 64; i += 256){                  // stage page bits (pad k 36..63 = 0)
    int r = i >> 6, k = i & 63;
    float v = (k < 36) ? vab[(size_t)(bb + r) * 48 + 12 + k] : 0.0f;
    int byte = (r * 128 + k * 2) ^ ((r & 7) << 4);
    *(unsigned short*)((char*)pb_lds + byte) = f2bf(v);
  }
  for (int i = tid; i < 128 * 12; i += 256){                  // offset-bit passthrough
    int r = i / 12, c = i - r * 12;
    out[(size_t)(bb + r) * 52 + c] = vab[(size_t)(bb + r) * 48 + c];
  }
  __syncthreads();

  const int lane = tid & 63, wv = tid >> 6;
  const int lo = lane & 31, hi = lane >> 5;
  const unsigned short* w1t = (const unsigned short*)(ws + OFF_W1T);

  // phase 1: h^T = W1^T @ pb^T
  #pragma unroll
  for (int art = 0; art < 2; ++art){
    const int hcol0 = (wv * 2 + art) * 32;
    bfr8 af[3];
    #pragma unroll
    for (int ks = 0; ks < 3; ++ks)
      af[ks] = *(const bfr8*)(w1t + (size_t)(hcol0 + lo) * 48 + 8 * hi + 16 * ks);
    for (int bct = 0; bct < 4; ++bct){
      f32x16v acc = zero16();
      #pragma unroll
      for (int ks = 0; ks < 3; ++ks){
        int row = bct * 32 + lo;
        int byte = row * 128 + ((16 * hi + 32 * ks) ^ ((row & 7) << 4));
        bfr8 bf = *(const bfr8*)((const char*)pb_lds + byte);
        acc = mfma32(af[ks], bf, acc);
      }
      int brow = bct * 32 + lo;
      #pragma unroll
      for (int w = 0; w < 4; ++w){
        u16x4 pk;
        #pragma unroll
        for (int rs = 0; rs < 4; ++rs){
          int hcol = hcol0 + rs + 8 * w + 4 * hi;
          float x = acc[4 * w + rs] + b1[hcol];
          // tanh-form gelu (|x| <~ 1 here; diff vs erf-gelu < 1e-4)
          float u = x * (0.7978845608028654f + 0.0356774081f * x * x);
          float t = exp2f(u * -2.885390081777927f);   // e^{-2u}
          float th = (1.0f - t) / (1.0f + t);
          pk[rs] = f2bf(0.5f * x * (1.0f + th));
        }
        int byte = (brow * 512 + (hcol0 + 8 * w + 4 * hi) * 2) ^ ((brow & 7) << 4);
        *(u16x4*)((char*)h_lds + byte) = pk;
      }
    }
  }
  __syncthreads();

  // phase 2: q^T = W2^T @ h^T -> Qws bf16 (folded invt*log2e)
  const unsigned short* w2t = (const unsigned short*)(ws + OFF_W2T);
  unsigned short* qws = (unsigned short*)(ws + OFF_Q);
  const int qcol0 = wv * 32;
  bfr8 af2[16];
  #pragma unroll
  for (int ks = 0; ks < 16; ++ks)
    af2[ks] = *(const bfr8*)(w2t + (size_t)(qcol0 + lo) * 256 + 8 * hi + 16 * ks);
  for (int bct = 0; bct < 4; ++bct){
    f32x16v acc = zero16();
    int brow = bct * 32 + lo;
    #pragma unroll
    for (int ks = 0; ks < 16; ++ks){
      int byte = brow * 512 + ((16 * hi + 32 * ks) ^ ((brow & 7) << 4));
      bfr8 bf = *(const bfr8*)((const char*)h_lds + byte);
      acc = mfma32(af2[ks], bf, acc);
    }
    #pragma unroll
    for (int w = 0; w < 4; ++w){
      u16x4 pk;
      #pragma unroll
      for (int rs = 0; rs < 4; ++rs){
        int qcol = qcol0 + rs + 8 * w + 4 * hi;
        pk[rs] = f2bf((acc[4 * w + rs] + b2[qcol]) * qscale);
      }
      *(u16x4*)(qws + (size_t)(bb + brow) * 128 + qcol0 + 8 * w + 4 * hi) = pk;
    }
  }
}

// ---------------- attention: K-split-in-WG, in-register softmax ------------
// 512 WGs x 512 thr (8 waves). Waves 0-3 = chunks 0-31, waves 4-7 = chunks
// 32-63, same 128 rows. Each half: own double-buffered 16KB K LDS. Halves
// combine via LDS overlay at the end (pre-normalization sums are linear).
__global__ __launch_bounds__(512, 4) void attn_kernel(const char* __restrict__ ws,
    float* __restrict__ out){
  __shared__ __align__(16) char smem[65536];    // [half][buf][16KB]; epilogue overlay

  const int tid = threadIdx.x;
  const int lane = tid & 63, wv = tid >> 6;
  const int half = wv >> 2, wq = wv & 3;
  const int ht = tid & 255;                     // staging index within half
  const int lo = lane & 31, hi = lane >> 5;
  const int bb = blockIdx.x * 128;

  const unsigned short* qws = (const unsigned short*)(ws + OFF_Q);
  const unsigned short* kws = (const unsigned short*)(ws + OFF_K);
  const unsigned short* vt  = (const unsigned short*)(ws + OFF_V);

  const int qrow = bb + wq * 32 + lo;
  bfr8 qf[8];                                   // Q row in registers (B-frag: col=lo)
  #pragma unroll
  for (int ks = 0; ks < 8; ++ks)
    qf[ks] = *(const bfr8*)(qws + (size_t)qrow * 128 + 16 * ks + 8 * hi);

  f32x16v acc0 = zero16(), acc1 = zero16();     // C: col=lo -> vcol, row=crow -> query

  char* myk = smem + half * 32768;
  const int cbase = half * 32;

  // prologue: stage this half's first chunk into buf 0
  {
    const u16x8* src = (const u16x8*)(kws + (size_t)cbase * 8192);
    u16x8* dst = (u16x8*)myk;
    #pragma unroll
    for (int i = 0; i < 4; ++i) dst[i * 256 + ht] = src[i * 256 + ht];
  }
  __syncthreads();

  for (int c = 0; c < 32; ++c){
    // issue next-chunk global loads early
    u16x8 st[4];
    {
      int nc = cbase + ((c < 31) ? c + 1 : 31);
      const u16x8* src = (const u16x8*)(kws + (size_t)nc * 8192);
      #pragma unroll
      for (int i = 0; i < 4; ++i) st[i] = src[i * 256 + ht];
    }

    // S^T = K @ Q^T: two 32-page tiles; lane holds one query (col=lo)
    const char* kb = myk + (c & 1) * 16384;
    f32x16v s0 = zero16(), s1 = zero16();
    #pragma unroll
    for (int ks = 0; ks < 8; ++ks){
      int cb = ((16 * ks + 8 * hi) * 2) ^ ((lo & 7) << 4);
      bfr8 k0 = *(const bfr8*)(kb + lo * 256 + cb);
      bfr8 k1 = *(const bfr8*)(kb + (32 + lo) * 256 + cb);
      s0 = mfma32(k0, qf[ks], s0);
      s1 = mfma32(k1, qf[ks], s1);
    }

    // V B-fragments straight from global (L2/L1-resident)
    int cg = cbase + c;
    bfr8 vf0[4], vf1[4];
    #pragma unroll
    for (int kt = 0; kt < 4; ++kt){
      vf0[kt] = *(const bfr8*)(vt + (size_t)lo * 4096 + cg * 64 + kt * 16 + 8 * hi);
      vf1[kt] = *(const bfr8*)(vt + (size_t)(32 + (lo & 15)) * 4096 + cg * 64 + kt * 16 + 8 * hi);
    }

    // in-register softmax numerator + pack to PV A-fragments
    bfr8 pa0, pa1, pa2, pa3;
    tile_pack(s0, pa0, pa1);                    // keys 0-15, 16-31
    tile_pack(s1, pa2, pa3);                    // keys 32-47, 48-63

    acc0 = mfma32(pa0, vf0[0], acc0);  acc1 = mfma32(pa0, vf1[0], acc1);
    acc0 = mfma32(pa1, vf0[1], acc0);  acc1 = mfma32(pa1, vf1[1], acc1);
    acc0 = mfma32(pa2, vf0[2], acc0);  acc1 = mfma32(pa2, vf1[2], acc1);
    acc0 = mfma32(pa3, vf0[3], acc0);  acc1 = mfma32(pa3, vf1[3], acc1);

    // write staged next chunk into the other buffer, then one barrier
    {
      u16x8* dst = (u16x8*)(myk + ((c + 1) & 1) * 16384);
      #pragma unroll
      for (int i = 0; i < 4; ++i) dst[i * 256 + ht] = st[i];
    }
    __syncthreads();
  }

  // ---- combine halves via LDS overlay (K buffers are dead now) ----
  float* comb0 = (float*)smem;                  // [128][32] f32, 16 KB
  float* comb1 = (float*)(smem + 16384);        // [128][12] f32, 6 KB
  if (half == 1){
    #pragma unroll
    for (int r = 0; r < 16; ++r){
      int row = wq * 32 + (r & 3) + 8 * (r >> 2) + 4 * hi;
      comb0[row * 32 + lo] = acc0[r];
      if (lo < 9) comb1[row * 12 + lo] = acc1[r];
    }
  }
  __syncthreads();
  if (half == 0){
    #pragma unroll
    for (int r = 0; r < 16; ++r){
      int row = wq * 32 + (r & 3) + 8 * (r >> 2) + 4 * hi;
      float n0 = acc0[r] + comb0[row * 32 + lo];
      float a1 = acc1[r] + ((lo < 9) ? comb1[row * 12 + lo] : 0.0f);
      float dn = __shfl(a1, (lane & 32) + 8, 64);   // denom = vcol 40 (lo==8)
      float dinv = 1.0f / dn;
      size_t q = (size_t)(bb + row);
      out[q * 52 + 12 + lo] = sigmoidf_(n0 * dinv);
      if (lo < 8) out[q * 52 + 44 + lo] = sigmoidf_(a1 * dinv);
    }
  }
}

extern "C" void kernel_launch(void* const* d_in, const int* in_sizes, int n_in,
                              void* d_out, int out_size, void* d_ws, size_t ws_size,
                              hipStream_t stream){
  const float* vab      = (const float*)d_in[0];
  const float* mappings = (const float*)d_in[1];
  const float* keys     = (const float*)d_in[2];
  const float* perms    = (const float*)d_in[3];
  const float* W1       = (const float*)d_in[4];
  const float* b1       = (const float*)d_in[5];
  const float* W2       = (const float*)d_in[6];
  const float* b2       = (const float*)d_in[7];
  const float* temp     = (const float*)d_in[8];
  float* out = (float*)d_out;
  char*  ws  = (char*)d_ws;
  if (ws_size < WS_NEEDED) return;   // loud failure instead of OOB corruption

  prep_kernel<<<1200, 256, 0, stream>>>(mappings, keys, perms, W1, W2, ws);
  mlp_kernel<<<512, 256, 0, stream>>>(vab, b1, b2, temp, ws, out);
  attn_kernel<<<512, 512, 0, stream>>>(ws, out);
}

// Round 5
// 230.702 us; speedup vs baseline: 1.1210x; 1.1210x over previous
//
#include <hip/hip_runtime.h>

// ---------------- problem constants ----------------
#define BATCH   65536
#define NPAGES  4096
#define KD      128

// ws layout (bytes). Total 18,309,120 B (~17.5 MB).
#define OFF_Q    0u          // Q bf16 [65536][128], pre-scaled by invt*log2e  16 MB
#define OFF_K    16777216u   // K bf16, 64-page chunks, XOR-swizzled            1 MB
#define OFF_V    17825792u   // V^T bf16 [48][4096] (aug: ones col 40)        384 KB
#define OFF_W1T  18219008u   // W1^T bf16 [256][48] (k padded 36->48)          24 KB
#define OFF_W2T  18243584u   // W2^T bf16 [128][256]                           64 KB
#define WS_NEEDED 18309120u

typedef short          bfr8   __attribute__((ext_vector_type(8)));
typedef unsigned short u16x8  __attribute__((ext_vector_type(8)));
typedef unsigned short u16x4  __attribute__((ext_vector_type(4)));
typedef unsigned int   u32x4  __attribute__((ext_vector_type(4)));
typedef float          f32x16v __attribute__((ext_vector_type(16)));

__device__ __forceinline__ unsigned short f2bf(float x){
  unsigned int u = __builtin_bit_cast(unsigned int, x);
  unsigned int r = (u + 0x7fffu + ((u >> 16) & 1u)) >> 16;   // RNE
  return (unsigned short)r;
}
__device__ __forceinline__ float sigmoidf_(float x){ return 1.0f / (1.0f + __expf(-x)); }

__device__ __forceinline__ f32x16v mfma32(bfr8 a, bfr8 b, f32x16v c){
  return __builtin_amdgcn_mfma_f32_32x32x16_bf16(a, b, c, 0, 0, 0);
}
__device__ __forceinline__ f32x16v zero16(){
  f32x16v v;
  #pragma unroll
  for (int i = 0; i < 16; ++i) v[i] = 0.f;
  return v;
}

// async global->LDS, 16B per lane, dest = ldsbase + lane*16 (linear, preserves pre-swizzle)
__device__ __forceinline__ void glds16(const void* g, void* l){
  __builtin_amdgcn_global_load_lds(
      (const __attribute__((address_space(1))) unsigned int*)g,
      (__attribute__((address_space(3))) unsigned int*)l, 16, 0, 0);
}

// exp2 + pack one 32-key S-tile into two PV A-fragments (keys 0-15, 16-31).
// Q was pre-scaled by invt*log2e, so P = exp2(S) directly (1 trans op/elem).
__device__ __forceinline__ void tile_pack(const f32x16v& s, bfr8& paA, bfr8& paB){
  unsigned w[8];
  #pragma unroll
  for (int p = 0; p < 8; ++p){
    float a = exp2f(s[2*p]);
    float b = exp2f(s[2*p+1]);
    asm("v_cvt_pk_bf16_f32 %0, %1, %2" : "=v"(w[p]) : "v"(a), "v"(b));
  }
  asm("v_permlane32_swap_b32 %0, %1" : "+v"(w[0]), "+v"(w[2]));
  asm("v_permlane32_swap_b32 %0, %1" : "+v"(w[1]), "+v"(w[3]));
  asm("v_permlane32_swap_b32 %0, %1" : "+v"(w[4]), "+v"(w[6]));
  asm("v_permlane32_swap_b32 %0, %1" : "+v"(w[5]), "+v"(w[7]));
  u32x4 t0 = {w[0], w[1], w[2], w[3]};
  u32x4 t1 = {w[4], w[5], w[6], w[7]};
  paA = __builtin_bit_cast(bfr8, t0);
  paB = __builtin_bit_cast(bfr8, t1);
}

// ---------------- prep: bf16 conversions / layouts ----------------
__global__ void prep_kernel(const float* __restrict__ mappings, const float* __restrict__ keys,
                            const float* __restrict__ perms, const float* __restrict__ W1,
                            const float* __restrict__ W2, char* __restrict__ ws){
  int t = blockIdx.x * 256 + threadIdx.x;
  if (t < 65536){                       // K: 4096 pages x 16 granules of 8 cols
    int p = t >> 4, c8 = t & 15;
    const float* src = keys + (size_t)p * 128 + c8 * 8;
    u16x8 val;
    #pragma unroll
    for (int j = 0; j < 8; ++j) val[j] = f2bf(src[j]);
    int r = p & 63, chunk = p >> 6;
    int byteoff = (r * 256 + c8 * 16) ^ ((r & 7) << 4);   // pre-swizzle (involution)
    *(u16x8*)(ws + OFF_K + (size_t)chunk * 16384 + byteoff) = val;
  } else if (t < 65536 + 12288){        // W1^T [256][48], k>=36 zero
    int i = t - 65536; int cc = i / 48, k = i - cc * 48;
    float v = (k < 36) ? W1[(size_t)k * 256 + cc] : 0.0f;
    ((unsigned short*)(ws + OFF_W1T))[cc * 48 + k] = f2bf(v);
  } else if (t < 65536 + 12288 + 32768){ // W2^T [128][256]
    int i = t - (65536 + 12288); int cc = i >> 8, k = i & 255;
    ((unsigned short*)(ws + OFF_W2T))[cc * 256 + k] = f2bf(W2[(size_t)k * 128 + cc]);
  } else {                              // V^T [48][4096]: rows 0..35 map[36+j], 36..39 perms, 40 ones, 41..47 zero
    int i = t - (65536 + 12288 + 32768); int j = i >> 12, p = i & 4095;
    float v;
    if (j < 36)      v = mappings[(size_t)p * 72 + 36 + j];
    else if (j < 40) v = perms[(size_t)p * 4 + (j - 36)];
    else if (j == 40) v = 1.0f;
    else             v = 0.0f;
    ((unsigned short*)(ws + OFF_V))[j * 4096 + p] = f2bf(v);
  }
}

// ---------------- MLP: query = gelu(pb@W1+b1)@W2+b2 -> Q bf16 (pre-scaled) --
__global__ __launch_bounds__(256, 2) void mlp_kernel(const float* __restrict__ vab,
    const float* __restrict__ b1, const float* __restrict__ b2,
    const float* __restrict__ temp_p, char* __restrict__ ws, float* __restrict__ out){
  __shared__ __align__(16) unsigned short pb_lds[128 * 64];   // swizzled bf16, 16 KB
  __shared__ __align__(16) unsigned short h_lds[128 * 256];   // swizzled bf16, 64 KB
  const int tid = threadIdx.x;
  const int bb = blockIdx.x * 128;
  const float qscale = 1.44269504088896f / fmaxf(fabsf(temp_p[0]), 0.1f);

  for (int i = tid; i < 128 * 64; i += 256){                  // stage page bits (pad k 36..63 = 0)
    int r = i >> 6, k = i & 63;
    float v = (k < 36) ? vab[(size_t)(bb + r) * 48 + 12 + k] : 0.0f;
    int byte = (r * 128 + k * 2) ^ ((r & 7) << 4);
    *(unsigned short*)((char*)pb_lds + byte) = f2bf(v);
  }
  for (int i = tid; i < 128 * 12; i += 256){                  // offset-bit passthrough
    int r = i / 12, c = i - r * 12;
    out[(size_t)(bb + r) * 52 + c] = vab[(size_t)(bb + r) * 48 + c];
  }
  __syncthreads();

  const int lane = tid & 63, wv = tid >> 6;
  const int lo = lane & 31, hi = lane >> 5;
  const unsigned short* w1t = (const unsigned short*)(ws + OFF_W1T);

  // phase 1: h^T = W1^T @ pb^T
  #pragma unroll
  for (int art = 0; art < 2; ++art){
    const int hcol0 = (wv * 2 + art) * 32;
    bfr8 af[3];
    #pragma unroll
    for (int ks = 0; ks < 3; ++ks)
      af[ks] = *(const bfr8*)(w1t + (size_t)(hcol0 + lo) * 48 + 8 * hi + 16 * ks);
    for (int bct = 0; bct < 4; ++bct){
      f32x16v acc = zero16();
      #pragma unroll
      for (int ks = 0; ks < 3; ++ks){
        int row = bct * 32 + lo;
        int byte = row * 128 + ((16 * hi + 32 * ks) ^ ((row & 7) << 4));
        bfr8 bf = *(const bfr8*)((const char*)pb_lds + byte);
        acc = mfma32(af[ks], bf, acc);
      }
      int brow = bct * 32 + lo;
      #pragma unroll
      for (int w = 0; w < 4; ++w){
        u16x4 pk;
        #pragma unroll
        for (int rs = 0; rs < 4; ++rs){
          int hcol = hcol0 + rs + 8 * w + 4 * hi;
          float x = acc[4 * w + rs] + b1[hcol];
          // tanh-form gelu (|x| <~ 1 here; diff vs erf-gelu < 1e-4)
          float u = x * (0.7978845608028654f + 0.0356774081f * x * x);
          float t = exp2f(u * -2.885390081777927f);   // e^{-2u}
          float th = (1.0f - t) / (1.0f + t);
          pk[rs] = f2bf(0.5f * x * (1.0f + th));
        }
        int byte = (brow * 512 + (hcol0 + 8 * w + 4 * hi) * 2) ^ ((brow & 7) << 4);
        *(u16x4*)((char*)h_lds + byte) = pk;
      }
    }
  }
  __syncthreads();

  // phase 2: q^T = W2^T @ h^T -> Qws bf16 (folded invt*log2e)
  const unsigned short* w2t = (const unsigned short*)(ws + OFF_W2T);
  unsigned short* qws = (unsigned short*)(ws + OFF_Q);
  const int qcol0 = wv * 32;
  bfr8 af2[16];
  #pragma unroll
  for (int ks = 0; ks < 16; ++ks)
    af2[ks] = *(const bfr8*)(w2t + (size_t)(qcol0 + lo) * 256 + 8 * hi + 16 * ks);
  for (int bct = 0; bct < 4; ++bct){
    f32x16v acc = zero16();
    int brow = bct * 32 + lo;
    #pragma unroll
    for (int ks = 0; ks < 16; ++ks){
      int byte = brow * 512 + ((16 * hi + 32 * ks) ^ ((brow & 7) << 4));
      bfr8 bf = *(const bfr8*)((const char*)h_lds + byte);
      acc = mfma32(af2[ks], bf, acc);
    }
    #pragma unroll
    for (int w = 0; w < 4; ++w){
      u16x4 pk;
      #pragma unroll
      for (int rs = 0; rs < 4; ++rs){
        int qcol = qcol0 + rs + 8 * w + 4 * hi;
        pk[rs] = f2bf((acc[4 * w + rs] + b2[qcol]) * qscale);
      }
      *(u16x4*)(qws + (size_t)(bb + brow) * 128 + qcol0 + 8 * w + 4 * hi) = pk;
    }
  }
}

// ---------------- attention: K-split-in-WG, in-register softmax ------------
// 512 WGs x 512 thr (8 waves). Waves 0-3 = chunks 0-31, waves 4-7 = chunks
// 32-63, same 128 rows. Double-buffered 16KB K LDS per half, staged via
// global_load_lds (no reg staging -> VGPR <= 128 for 2 WGs/CU).
__global__ __launch_bounds__(512, 2) void attn_kernel(const char* __restrict__ ws,
    float* __restrict__ out){
  __shared__ __align__(16) char smem[65536];    // [half][buf][16KB]; epilogue overlay

  const int tid = threadIdx.x;
  const int lane = tid & 63, wv = tid >> 6;
  const int half = wv >> 2, wq = wv & 3;
  const int lo = lane & 31, hi = lane >> 5;
  const int bb = blockIdx.x * 128;

  const unsigned short* qws = (const unsigned short*)(ws + OFF_Q);
  const char* kbase = ws + OFF_K;
  const unsigned short* vt  = (const unsigned short*)(ws + OFF_V);

  const int qrow = bb + wq * 32 + lo;
  bfr8 qf[8];                                   // Q row in registers (B-frag: col=lo)
  #pragma unroll
  for (int ks = 0; ks < 8; ++ks)
    qf[ks] = *(const bfr8*)(qws + (size_t)qrow * 128 + 16 * ks + 8 * hi);

  f32x16v acc0 = zero16(), acc1 = zero16();     // C: col=lo -> vcol, row=crow -> query

  char* myk = smem + half * 32768;
  const int cbase = half * 32;
  const int stoff = wq * 4096 + lane * 16;      // this wave's 4KB slice (lane*16 in src only)

  // prologue: stage this half's first chunk into buf 0
  #pragma unroll
  for (int i = 0; i < 4; ++i)
    glds16(kbase + (size_t)cbase * 16384 + stoff + i * 1024,
           myk + wq * 4096 + i * 1024);
  __syncthreads();

  for (int c = 0; c < 32; ++c){
    // issue next-chunk DMA into the other buffer (safe: it was last read pre-barrier)
    {
      int nc = cbase + ((c < 31) ? c + 1 : 31);
      char* dstb = myk + ((c + 1) & 1) * 16384 + wq * 4096;
      #pragma unroll
      for (int i = 0; i < 4; ++i)
        glds16(kbase + (size_t)nc * 16384 + stoff + i * 1024, dstb + i * 1024);
    }

    // S^T = K @ Q^T: two 32-page tiles; lane holds one query (col=lo)
    const char* kb = myk + (c & 1) * 16384;
    f32x16v s0 = zero16(), s1 = zero16();
    #pragma unroll
    for (int ks = 0; ks < 8; ++ks){
      int cb = ((16 * ks + 8 * hi) * 2) ^ ((lo & 7) << 4);
      bfr8 k0 = *(const bfr8*)(kb + lo * 256 + cb);
      bfr8 k1 = *(const bfr8*)(kb + (32 + lo) * 256 + cb);
      s0 = mfma32(k0, qf[ks], s0);
      s1 = mfma32(k1, qf[ks], s1);
    }

    // V B-fragments straight from global (L2/L1-resident)
    int cg = cbase + c;
    bfr8 vf0[4], vf1[4];
    #pragma unroll
    for (int kt = 0; kt < 4; ++kt){
      vf0[kt] = *(const bfr8*)(vt + (size_t)lo * 4096 + cg * 64 + kt * 16 + 8 * hi);
      vf1[kt] = *(const bfr8*)(vt + (size_t)(32 + (lo & 15)) * 4096 + cg * 64 + kt * 16 + 8 * hi);
    }

    // in-register softmax numerator + pack to PV A-fragments
    bfr8 pa0, pa1, pa2, pa3;
    tile_pack(s0, pa0, pa1);                    // keys 0-15, 16-31
    tile_pack(s1, pa2, pa3);                    // keys 32-47, 48-63

    acc0 = mfma32(pa0, vf0[0], acc0);  acc1 = mfma32(pa0, vf1[0], acc1);
    acc0 = mfma32(pa1, vf0[1], acc0);  acc1 = mfma32(pa1, vf1[1], acc1);
    acc0 = mfma32(pa2, vf0[2], acc0);  acc1 = mfma32(pa2, vf1[2], acc1);
    acc0 = mfma32(pa3, vf0[3], acc0);  acc1 = mfma32(pa3, vf1[3], acc1);

    __syncthreads();   // drains DMA (vmcnt) + LDS reads; next buffer ready
  }

  // ---- combine halves via LDS overlay (K buffers are dead now) ----
  float* comb0 = (float*)smem;                  // [128][32] f32, 16 KB
  float* comb1 = (float*)(smem + 16384);        // [128][12] f32, 6 KB
  if (half == 1){
    #pragma unroll
    for (int r = 0; r < 16; ++r){
      int row = wq * 32 + (r & 3) + 8 * (r >> 2) + 4 * hi;
      comb0[row * 32 + lo] = acc0[r];
      if (lo < 9) comb1[row * 12 + lo] = acc1[r];
    }
  }
  __syncthreads();
  if (half == 0){
    #pragma unroll
    for (int r = 0; r < 16; ++r){
      int row = wq * 32 + (r & 3) + 8 * (r >> 2) + 4 * hi;
      float n0 = acc0[r] + comb0[row * 32 + lo];
      float a1 = acc1[r] + ((lo < 9) ? comb1[row * 12 + lo] : 0.0f);
      float dn = __shfl(a1, (lane & 32) + 8, 64);   // denom = vcol 40 (lo==8)
      float dinv = 1.0f / dn;
      size_t q = (size_t)(bb + row);
      out[q * 52 + 12 + lo] = sigmoidf_(n0 * dinv);
      if (lo < 8) out[q * 52 + 44 + lo] = sigmoidf_(a1 * dinv);
    }
  }
}

extern "C" void kernel_launch(void* const* d_in, const int* in_sizes, int n_in,
                              void* d_out, int out_size, void* d_ws, size_t ws_size,
                              hipStream_t stream){
  const float* vab      = (const float*)d_in[0];
  const float* mappings = (const float*)d_in[1];
  const float* keys     = (const float*)d_in[2];
  const float* perms    = (const float*)d_in[3];
  const float* W1       = (const float*)d_in[4];
  const float* b1       = (const float*)d_in[5];
  const float* W2       = (const float*)d_in[6];
  const float* b2       = (const float*)d_in[7];
  const float* temp     = (const float*)d_in[8];
  float* out = (float*)d_out;
  char*  ws  = (char*)d_ws;
  if (ws_size < WS_NEEDED) return;   // loud failure instead of OOB corruption

  prep_kernel<<<1200, 256, 0, stream>>>(mappings, keys, perms, W1, W2, ws);
  mlp_kernel<<<512, 256, 0, stream>>>(vab, b1, b2, temp, ws, out);
  attn_kernel<<<512, 512, 0, stream>>>(ws, out);
}

// Round 6
// 163.072 us; speedup vs baseline: 1.5860x; 1.4147x over previous
//
#include <hip/hip_runtime.h>

// ---------------- problem constants ----------------
#define BATCH   65536
#define NPAGES  4096
#define KD      128

// ws layout (bytes). Total 18,309,120 B (~17.5 MB).
#define OFF_Q    0u          // Q bf16 [65536][128], pre-scaled by invt*log2e  16 MB
#define OFF_K    16777216u   // K bf16, 64-page chunks, XOR-swizzled            1 MB
#define OFF_V    17825792u   // V^T bf16 [48][4096] (aug: ones col 40)        384 KB
#define OFF_W1T  18219008u   // W1^T bf16 [256][48] (k padded 36->48)          24 KB
#define OFF_W2T  18243584u   // W2^T bf16 [128][256]                           64 KB
#define WS_NEEDED 18309120u

typedef short          bfr8   __attribute__((ext_vector_type(8)));
typedef unsigned short u16x8  __attribute__((ext_vector_type(8)));
typedef unsigned short u16x4  __attribute__((ext_vector_type(4)));
typedef unsigned int   u32x4  __attribute__((ext_vector_type(4)));
typedef float          f32x16v __attribute__((ext_vector_type(16)));

__device__ __forceinline__ unsigned short f2bf(float x){
  unsigned int u = __builtin_bit_cast(unsigned int, x);
  unsigned int r = (u + 0x7fffu + ((u >> 16) & 1u)) >> 16;   // RNE
  return (unsigned short)r;
}
__device__ __forceinline__ float sigmoidf_(float x){ return 1.0f / (1.0f + __expf(-x)); }

__device__ __forceinline__ f32x16v mfma32(bfr8 a, bfr8 b, f32x16v c){
  return __builtin_amdgcn_mfma_f32_32x32x16_bf16(a, b, c, 0, 0, 0);
}
__device__ __forceinline__ f32x16v zero16(){
  f32x16v v;
  #pragma unroll
  for (int i = 0; i < 16; ++i) v[i] = 0.f;
  return v;
}

// async global->LDS, 16B per lane, dest = ldsbase + lane*16 (linear, preserves pre-swizzle)
__device__ __forceinline__ void glds16(const void* g, void* l){
  __builtin_amdgcn_global_load_lds(
      (const __attribute__((address_space(1))) unsigned int*)g,
      (__attribute__((address_space(3))) unsigned int*)l, 16, 0, 0);
}

// exp2 + pack one 32-key S^T-tile into two PV A-fragments (keys 0-15, 16-31).
// Q pre-scaled by invt*log2e -> P = exp2(S) directly.
__device__ __forceinline__ void tile_pack(const f32x16v& s, bfr8& paA, bfr8& paB){
  unsigned w[8];
  #pragma unroll
  for (int p = 0; p < 8; ++p){
    float a = exp2f(s[2*p]);
    float b = exp2f(s[2*p+1]);
    asm("v_cvt_pk_bf16_f32 %0, %1, %2" : "=v"(w[p]) : "v"(a), "v"(b));
  }
  asm("v_permlane32_swap_b32 %0, %1" : "+v"(w[0]), "+v"(w[2]));
  asm("v_permlane32_swap_b32 %0, %1" : "+v"(w[1]), "+v"(w[3]));
  asm("v_permlane32_swap_b32 %0, %1" : "+v"(w[4]), "+v"(w[6]));
  asm("v_permlane32_swap_b32 %0, %1" : "+v"(w[5]), "+v"(w[7]));
  u32x4 t0 = {w[0], w[1], w[2], w[3]};
  u32x4 t1 = {w[4], w[5], w[6], w[7]};
  paA = __builtin_bit_cast(bfr8, t0);
  paB = __builtin_bit_cast(bfr8, t1);
}

// ---------------- prep: bf16 conversions / layouts ----------------
__global__ void prep_kernel(const float* __restrict__ mappings, const float* __restrict__ keys,
                            const float* __restrict__ perms, const float* __restrict__ W1,
                            const float* __restrict__ W2, char* __restrict__ ws){
  int t = blockIdx.x * 256 + threadIdx.x;
  if (t < 65536){                       // K: 4096 pages x 16 granules of 8 cols
    int p = t >> 4, c8 = t & 15;
    const float* src = keys + (size_t)p * 128 + c8 * 8;
    u16x8 val;
    #pragma unroll
    for (int j = 0; j < 8; ++j) val[j] = f2bf(src[j]);
    int r = p & 63, chunk = p >> 6;
    int byteoff = (r * 256 + c8 * 16) ^ ((r & 7) << 4);   // pre-swizzle (involution)
    *(u16x8*)(ws + OFF_K + (size_t)chunk * 16384 + byteoff) = val;
  } else if (t < 65536 + 12288){        // W1^T [256][48], k>=36 zero
    int i = t - 65536; int cc = i / 48, k = i - cc * 48;
    float v = (k < 36) ? W1[(size_t)k * 256 + cc] : 0.0f;
    ((unsigned short*)(ws + OFF_W1T))[cc * 48 + k] = f2bf(v);
  } else if (t < 65536 + 12288 + 32768){ // W2^T [128][256]
    int i = t - (65536 + 12288); int cc = i >> 8, k = i & 255;
    ((unsigned short*)(ws + OFF_W2T))[cc * 256 + k] = f2bf(W2[(size_t)k * 128 + cc]);
  } else {                              // V^T [48][4096]: rows 0..35 map[36+j], 36..39 perms, 40 ones, 41..47 zero
    int i = t - (65536 + 12288 + 32768); int j = i >> 12, p = i & 4095;
    float v;
    if (j < 36)      v = mappings[(size_t)p * 72 + 36 + j];
    else if (j < 40) v = perms[(size_t)p * 4 + (j - 36)];
    else if (j == 40) v = 1.0f;
    else             v = 0.0f;
    ((unsigned short*)(ws + OFF_V))[j * 4096 + p] = f2bf(v);
  }
}

// ---------------- MLP: query = gelu(pb@W1+b1)@W2+b2 -> Q bf16 (pre-scaled) --
__global__ __launch_bounds__(256, 2) void mlp_kernel(const float* __restrict__ vab,
    const float* __restrict__ b1, const float* __restrict__ b2,
    const float* __restrict__ temp_p, char* __restrict__ ws, float* __restrict__ out){
  __shared__ __align__(16) unsigned short pb_lds[128 * 64];   // swizzled bf16, 16 KB
  __shared__ __align__(16) unsigned short h_lds[128 * 256];   // swizzled bf16, 64 KB
  const int tid = threadIdx.x;
  const int bb = blockIdx.x * 128;
  const float qscale = 1.44269504088896f / fmaxf(fabsf(temp_p[0]), 0.1f);

  for (int i = tid; i < 128 * 64; i += 256){                  // stage page bits (pad k 36..63 = 0)
    int r = i >> 6, k = i & 63;
    float v = (k < 36) ? vab[(size_t)(bb + r) * 48 + 12 + k] : 0.0f;
    int byte = (r * 128 + k * 2) ^ ((r & 7) << 4);
    *(unsigned short*)((char*)pb_lds + byte) = f2bf(v);
  }
  for (int i = tid; i < 128 * 12; i += 256){                  // offset-bit passthrough
    int r = i / 12, c = i - r * 12;
    out[(size_t)(bb + r) * 52 + c] = vab[(size_t)(bb + r) * 48 + c];
  }
  __syncthreads();

  const int lane = tid & 63, wv = tid >> 6;
  const int lo = lane & 31, hi = lane >> 5;
  const unsigned short* w1t = (const unsigned short*)(ws + OFF_W1T);

  // phase 1: h^T = W1^T @ pb^T
  #pragma unroll
  for (int art = 0; art < 2; ++art){
    const int hcol0 = (wv * 2 + art) * 32;
    bfr8 af[3];
    #pragma unroll
    for (int ks = 0; ks < 3; ++ks)
      af[ks] = *(const bfr8*)(w1t + (size_t)(hcol0 + lo) * 48 + 8 * hi + 16 * ks);
    for (int bct = 0; bct < 4; ++bct){
      f32x16v acc = zero16();
      #pragma unroll
      for (int ks = 0; ks < 3; ++ks){
        int row = bct * 32 + lo;
        int byte = row * 128 + ((16 * hi + 32 * ks) ^ ((row & 7) << 4));
        bfr8 bf = *(const bfr8*)((const char*)pb_lds + byte);
        acc = mfma32(af[ks], bf, acc);
      }
      int brow = bct * 32 + lo;
      #pragma unroll
      for (int w = 0; w < 4; ++w){
        u16x4 pk;
        #pragma unroll
        for (int rs = 0; rs < 4; ++rs){
          int hcol = hcol0 + rs + 8 * w + 4 * hi;
          float x = acc[4 * w + rs] + b1[hcol];
          // tanh-form gelu (|x| <~ 1 here; diff vs erf-gelu < 1e-4)
          float u = x * (0.7978845608028654f + 0.0356774081f * x * x);
          float t = exp2f(u * -2.885390081777927f);   // e^{-2u}
          float th = (1.0f - t) / (1.0f + t);
          pk[rs] = f2bf(0.5f * x * (1.0f + th));
        }
        int byte = (brow * 512 + (hcol0 + 8 * w + 4 * hi) * 2) ^ ((brow & 7) << 4);
        *(u16x4*)((char*)h_lds + byte) = pk;
      }
    }
  }
  __syncthreads();

  // phase 2: q^T = W2^T @ h^T -> Qws bf16 (folded invt*log2e)
  const unsigned short* w2t = (const unsigned short*)(ws + OFF_W2T);
  unsigned short* qws = (unsigned short*)(ws + OFF_Q);
  const int qcol0 = wv * 32;
  bfr8 af2[16];
  #pragma unroll
  for (int ks = 0; ks < 16; ++ks)
    af2[ks] = *(const bfr8*)(w2t + (size_t)(qcol0 + lo) * 256 + 8 * hi + 16 * ks);
  for (int bct = 0; bct < 4; ++bct){
    f32x16v acc = zero16();
    int brow = bct * 32 + lo;
    #pragma unroll
    for (int ks = 0; ks < 16; ++ks){
      int byte = brow * 512 + ((16 * hi + 32 * ks) ^ ((brow & 7) << 4));
      bfr8 bf = *(const bfr8*)((const char*)h_lds + byte);
      acc = mfma32(af2[ks], bf, acc);
    }
    #pragma unroll
    for (int w = 0; w < 4; ++w){
      u16x4 pk;
      #pragma unroll
      for (int rs = 0; rs < 4; ++rs){
        int qcol = qcol0 + rs + 8 * w + 4 * hi;
        pk[rs] = f2bf((acc[4 * w + rs] + b2[qcol]) * qscale);
      }
      *(u16x4*)(qws + (size_t)(bb + brow) * 128 + qcol0 + 8 * w + 4 * hi) = pk;
    }
  }
}

// ---------------- attention: 64 rows/wave dual-tile, K-split-in-WG ---------
// 512 WGs x 256 thr (4 waves). wave = (sub = rows sub*64..+64, half = K-half).
// Per chunk: two key-phases (0-31, 32-63); each K-frag ds_read feeds 2 Q-tiles.
__global__ __launch_bounds__(256, 2) void attn_kernel(const char* __restrict__ ws,
    float* __restrict__ out){
  __shared__ __align__(16) char smem[65536];    // [half][buf][16KB]; epilogue overlay

  const int tid = threadIdx.x;
  const int lane = tid & 63, wv = tid >> 6;
  const int half = wv >> 1, sub = wv & 1;
  const int lo = lane & 31, hi = lane >> 5;
  const int bb = blockIdx.x * 128;

  const unsigned short* qws = (const unsigned short*)(ws + OFF_Q);
  const char* kbase = ws + OFF_K;
  const unsigned short* vt  = (const unsigned short*)(ws + OFF_V);

  const int r0 = bb + sub * 64;
  bfr8 qfA[8], qfB[8];                          // two Q-tiles (B-frag: col=lo)
  #pragma unroll
  for (int ks = 0; ks < 8; ++ks){
    qfA[ks] = *(const bfr8*)(qws + (size_t)(r0 + lo) * 128 + 16 * ks + 8 * hi);
    qfB[ks] = *(const bfr8*)(qws + (size_t)(r0 + 32 + lo) * 128 + 16 * ks + 8 * hi);
  }

  f32x16v accA0 = zero16(), accA1 = zero16();
  f32x16v accB0 = zero16(), accB1 = zero16();

  char* myk = smem + half * 32768;
  const int cbase = half * 32;

  // prologue: stage this half's first chunk into buf 0 (wave covers sub*8KB)
  #pragma unroll
  for (int i = 0; i < 8; ++i)
    glds16(kbase + (size_t)cbase * 16384 + sub * 8192 + lane * 16 + i * 1024,
           myk + sub * 8192 + i * 1024);
  __syncthreads();

  for (int c = 0; c < 32; ++c){
    if (c < 31){                                // issue next-chunk DMA
      const char* src = kbase + (size_t)(cbase + c + 1) * 16384 + sub * 8192 + lane * 16;
      char* dst = myk + ((c + 1) & 1) * 16384 + sub * 8192;
      #pragma unroll
      for (int i = 0; i < 8; ++i) glds16(src + i * 1024, dst + i * 1024);
    }

    const char* kb = myk + (c & 1) * 16384;
    const int cg = cbase + c;

    // ---- phase 1: keys 0..31 ----
    {
      f32x16v sA = zero16(), sB = zero16();
      #pragma unroll
      for (int ks = 0; ks < 8; ++ks){
        int cb = ((16 * ks + 8 * hi) * 2) ^ ((lo & 7) << 4);
        bfr8 k0 = *(const bfr8*)(kb + lo * 256 + cb);
        sA = mfma32(k0, qfA[ks], sA);
        sB = mfma32(k0, qfB[ks], sB);
      }
      bfr8 v00 = *(const bfr8*)(vt + (size_t)lo * 4096 + cg * 64 + 8 * hi);
      bfr8 v01 = *(const bfr8*)(vt + (size_t)lo * 4096 + cg * 64 + 16 + 8 * hi);
      bfr8 v10 = *(const bfr8*)(vt + (size_t)(32 + (lo & 15)) * 4096 + cg * 64 + 8 * hi);
      bfr8 v11 = *(const bfr8*)(vt + (size_t)(32 + (lo & 15)) * 4096 + cg * 64 + 16 + 8 * hi);
      bfr8 p0, p1;
      tile_pack(sA, p0, p1);
      accA0 = mfma32(p0, v00, accA0);  accA0 = mfma32(p1, v01, accA0);
      accA1 = mfma32(p0, v10, accA1);  accA1 = mfma32(p1, v11, accA1);
      tile_pack(sB, p0, p1);
      accB0 = mfma32(p0, v00, accB0);  accB0 = mfma32(p1, v01, accB0);
      accB1 = mfma32(p0, v10, accB1);  accB1 = mfma32(p1, v11, accB1);
    }
    // ---- phase 2: keys 32..63 ----
    {
      f32x16v sA = zero16(), sB = zero16();
      #pragma unroll
      for (int ks = 0; ks < 8; ++ks){
        int cb = ((16 * ks + 8 * hi) * 2) ^ ((lo & 7) << 4);
        bfr8 k1 = *(const bfr8*)(kb + (32 + lo) * 256 + cb);
        sA = mfma32(k1, qfA[ks], sA);
        sB = mfma32(k1, qfB[ks], sB);
      }
      bfr8 v00 = *(const bfr8*)(vt + (size_t)lo * 4096 + cg * 64 + 32 + 8 * hi);
      bfr8 v01 = *(const bfr8*)(vt + (size_t)lo * 4096 + cg * 64 + 48 + 8 * hi);
      bfr8 v10 = *(const bfr8*)(vt + (size_t)(32 + (lo & 15)) * 4096 + cg * 64 + 32 + 8 * hi);
      bfr8 v11 = *(const bfr8*)(vt + (size_t)(32 + (lo & 15)) * 4096 + cg * 64 + 48 + 8 * hi);
      bfr8 p0, p1;
      tile_pack(sA, p0, p1);
      accA0 = mfma32(p0, v00, accA0);  accA0 = mfma32(p1, v01, accA0);
      accA1 = mfma32(p0, v10, accA1);  accA1 = mfma32(p1, v11, accA1);
      tile_pack(sB, p0, p1);
      accB0 = mfma32(p0, v00, accB0);  accB0 = mfma32(p1, v01, accB0);
      accB1 = mfma32(p0, v10, accB1);  accB1 = mfma32(p1, v11, accB1);
    }
    __syncthreads();   // drains DMA (vmcnt) + LDS reads; next buffer ready
  }

  // ---- combine halves via LDS overlay (K buffers are dead now) ----
  float* comb0 = (float*)smem;                  // [128][32] f32, 16 KB
  float* comb1 = (float*)(smem + 16384);        // [128][12] f32, 6 KB
  if (half == 1){
    #pragma unroll
    for (int r = 0; r < 16; ++r){
      int rl = sub * 64 + (r & 3) + 8 * (r >> 2) + 4 * hi;
      comb0[rl * 32 + lo] = accA0[r];
      comb0[(rl + 32) * 32 + lo] = accB0[r];
      if (lo < 9){
        comb1[rl * 12 + lo] = accA1[r];
        comb1[(rl + 32) * 12 + lo] = accB1[r];
      }
    }
  }
  __syncthreads();
  if (half == 0){
    #pragma unroll
    for (int r = 0; r < 16; ++r){
      int rl = sub * 64 + (r & 3) + 8 * (r >> 2) + 4 * hi;
      {
        float n0 = accA0[r] + comb0[rl * 32 + lo];
        float a1 = accA1[r] + ((lo < 9) ? comb1[rl * 12 + lo] : 0.0f);
        float dn = __shfl(a1, (lane & 32) + 8, 64);   // denom = vcol 40 (lo==8)
        float di = 1.0f / dn;
        size_t q = (size_t)(bb + rl);
        out[q * 52 + 12 + lo] = sigmoidf_(n0 * di);
        if (lo < 8) out[q * 52 + 44 + lo] = sigmoidf_(a1 * di);
      }
      {
        float n0 = accB0[r] + comb0[(rl + 32) * 32 + lo];
        float a1 = accB1[r] + ((lo < 9) ? comb1[(rl + 32) * 12 + lo] : 0.0f);
        float dn = __shfl(a1, (lane & 32) + 8, 64);
        float di = 1.0f / dn;
        size_t q = (size_t)(bb + rl + 32);
        out[q * 52 + 12 + lo] = sigmoidf_(n0 * di);
        if (lo < 8) out[q * 52 + 44 + lo] = sigmoidf_(a1 * di);
      }
    }
  }
}

extern "C" void kernel_launch(void* const* d_in, const int* in_sizes, int n_in,
                              void* d_out, int out_size, void* d_ws, size_t ws_size,
                              hipStream_t stream){
  const float* vab      = (const float*)d_in[0];
  const float* mappings = (const float*)d_in[1];
  const float* keys     = (const float*)d_in[2];
  const float* perms    = (const float*)d_in[3];
  const float* W1       = (const float*)d_in[4];
  const float* b1       = (const float*)d_in[5];
  const float* W2       = (const float*)d_in[6];
  const float* b2       = (const float*)d_in[7];
  const float* temp     = (const float*)d_in[8];
  float* out = (float*)d_out;
  char*  ws  = (char*)d_ws;
  if (ws_size < WS_NEEDED) return;   // loud failure instead of OOB corruption

  prep_kernel<<<1200, 256, 0, stream>>>(mappings, keys, perms, W1, W2, ws);
  mlp_kernel<<<512, 256, 0, stream>>>(vab, b1, b2, temp, ws, out);
  attn_kernel<<<512, 256, 0, stream>>>(ws, out);
}